// Round 4
// baseline (1108.475 us; speedup 1.0000x reference)
//
#include <hip/hip_runtime.h>
#include <hip/hip_bf16.h>
#include <math.h>

typedef __hip_bfloat16 bf16;
typedef __attribute__((ext_vector_type(8))) short short8;
typedef __attribute__((ext_vector_type(4))) float f32x4;

// ---------- helpers ----------

__device__ __forceinline__ short f2bs(float x) {
  bf16 h = __float2bfloat16(x);
  return *reinterpret_cast<short*>(&h);
}

__device__ __forceinline__ float bs2f(short s) {
  unsigned int u = ((unsigned int)(unsigned short)s) << 16;
  return __uint_as_float(u);
}

// split x into hi (bf16) + lo (bf16 of exact residual); hi+lo ~ 2^-18 accurate
__device__ __forceinline__ void splitbf(float x, short& hi, short& lo) {
  hi = f2bs(x);
  lo = f2bs(x - bs2f(hi));
}

// load 4 consecutive bf16 and widen to float4 (exact)
__device__ __forceinline__ float4 ldbf4(const bf16* p) {
  const unsigned int* u = (const unsigned int*)p;
  unsigned int a = u[0], b = u[1];
  float4 f;
  f.x = __uint_as_float(a << 16);
  f.y = __uint_as_float(a & 0xffff0000u);
  f.z = __uint_as_float(b << 16);
  f.w = __uint_as_float(b & 0xffff0000u);
  return f;
}

// XOR swizzle: row-major [rows][64 floats], 16B chunk c4 xored with row bits.
__device__ __forceinline__ int swz(int r, int c4) {
  return (r << 6) + ((c4 ^ ((r >> 2) & 7)) << 2);
}

__device__ __forceinline__ float ex2(float x) {
  return __builtin_amdgcn_exp2f(x);
}

// ---------- MFMA NT GEMM: C[m,n] = sum_k A[m,k] * Bt[n,k] + bias[n] ----------
// M=4096, N=1024, K=1024. 128x128 tile, 4 waves, 16x16x32 bf16 MFMA.
// SPLIT: hi/lo split-bf16 (3 MFMA passes) for ~fp32 accuracy (q,k proj).
// A_IS_BF16: A source is bf16 (out proj), else fp32. Bt/bias always fp32.
// mode 0: fp32 out scattered to [B,H,T,hd]; mode 1: bf16 out [B,H,T,hd];
// mode 2: fp32 out row-major [M,N].
template <bool A_IS_BF16, bool SPLIT>
__device__ __forceinline__ void gemm_body(const void* __restrict__ Ap,
                                          const float* __restrict__ Bt,
                                          const float* __restrict__ bias,
                                          void* __restrict__ outp, int mode) {
  __shared__ alignas(16) bf16 Ah[128 * 32];
  __shared__ alignas(16) bf16 Bh[128 * 32];
  __shared__ alignas(16) bf16 Al[SPLIT ? 128 * 32 : 1];
  __shared__ alignas(16) bf16 Bl[SPLIT ? 128 * 32 : 1];
  const int tid = threadIdx.x;
  const int wave = tid >> 6;
  const int lane = tid & 63;
  const int wm = wave >> 1, wn = wave & 1;
  const int tm0 = blockIdx.x * 128, tn0 = blockIdx.y * 128;
  const int lrow = lane & 15;  // m (A frag) / n (B frag)
  const int kq = lane >> 4;    // k-quad

  f32x4 acc[4][4];
#pragma unroll
  for (int i = 0; i < 4; ++i)
#pragma unroll
    for (int j = 0; j < 4; ++j) acc[i][j] = (f32x4){0.f, 0.f, 0.f, 0.f};

  for (int k0 = 0; k0 < 1024; k0 += 32) {
    __syncthreads();
#pragma unroll
    for (int rep = 0; rep < 2; ++rep) {
      const int idx = rep * 256 + tid;  // 0..511: 128 rows x 4 chunks(8 elems)
      const int row = idx >> 2;
      const int c8 = (idx & 3) * 8;
      // A chunk
      if (A_IS_BF16) {
        *(short8*)(Ah + row * 32 + c8) = *(const short8*)(
            (const bf16*)Ap + (size_t)(tm0 + row) * 1024 + k0 + c8);
      } else {
        const float* ga =
            (const float*)Ap + (size_t)(tm0 + row) * 1024 + k0 + c8;
        float4 f0 = *(const float4*)ga;
        float4 f1 = *(const float4*)(ga + 4);
        float av[8] = {f0.x, f0.y, f0.z, f0.w, f1.x, f1.y, f1.z, f1.w};
        short8 sh, sl;
#pragma unroll
        for (int e = 0; e < 8; ++e) {
          short hi, lo;
          splitbf(av[e], hi, lo);
          sh[e] = hi;
          sl[e] = lo;
        }
        *(short8*)(Ah + row * 32 + c8) = sh;
        if (SPLIT) *(short8*)(Al + row * 32 + c8) = sl;
      }
      // B chunk (always fp32 source)
      const float* gb = Bt + (size_t)(tn0 + row) * 1024 + k0 + c8;
      float4 g0 = *(const float4*)gb;
      float4 g1 = *(const float4*)(gb + 4);
      float bv[8] = {g0.x, g0.y, g0.z, g0.w, g1.x, g1.y, g1.z, g1.w};
      short8 sh, sl;
#pragma unroll
      for (int e = 0; e < 8; ++e) {
        short hi, lo;
        splitbf(bv[e], hi, lo);
        sh[e] = hi;
        sl[e] = lo;
      }
      *(short8*)(Bh + row * 32 + c8) = sh;
      if (SPLIT) *(short8*)(Bl + row * 32 + c8) = sl;
    }
    __syncthreads();
    short8 afh[4], bfh[4];
#pragma unroll
    for (int i = 0; i < 4; ++i)
      afh[i] = *(const short8*)(Ah + (wm * 64 + i * 16 + lrow) * 32 + kq * 8);
#pragma unroll
    for (int j = 0; j < 4; ++j)
      bfh[j] = *(const short8*)(Bh + (wn * 64 + j * 16 + lrow) * 32 + kq * 8);
#pragma unroll
    for (int i = 0; i < 4; ++i)
#pragma unroll
      for (int j = 0; j < 4; ++j)
        acc[i][j] = __builtin_amdgcn_mfma_f32_16x16x32_bf16(afh[i], bfh[j],
                                                            acc[i][j], 0, 0, 0);
    if (SPLIT) {
      short8 afl[4], bfl[4];
#pragma unroll
      for (int i = 0; i < 4; ++i)
        afl[i] = *(const short8*)(Al + (wm * 64 + i * 16 + lrow) * 32 + kq * 8);
#pragma unroll
      for (int j = 0; j < 4; ++j)
        bfl[j] = *(const short8*)(Bl + (wn * 64 + j * 16 + lrow) * 32 + kq * 8);
#pragma unroll
      for (int i = 0; i < 4; ++i)
#pragma unroll
        for (int j = 0; j < 4; ++j) {
          acc[i][j] = __builtin_amdgcn_mfma_f32_16x16x32_bf16(
              afh[i], bfl[j], acc[i][j], 0, 0, 0);
          acc[i][j] = __builtin_amdgcn_mfma_f32_16x16x32_bf16(
              afl[i], bfh[j], acc[i][j], 0, 0, 0);
        }
    }
  }

  // epilogue: C row = wm*64 + i*16 + kq*4 + r ; col = wn*64 + j*16 + lrow
#pragma unroll
  for (int j = 0; j < 4; ++j) {
    const int n = tn0 + wn * 64 + j * 16 + lrow;
    const float bval = bias[n];
#pragma unroll
    for (int i = 0; i < 4; ++i) {
      const int rowb = wm * 64 + i * 16 + kq * 4;
#pragma unroll
      for (int r = 0; r < 4; ++r) {
        const int m = tm0 + rowb + r;
        const float val = acc[i][j][r] + bval;
        if (mode == 0) {
          const int b = m >> 10, t = m & 1023, hh = n >> 6, d = n & 63;
          ((float*)outp)[((size_t)((b << 4) + hh) << 16) + (t << 6) + d] = val;
        } else if (mode == 1) {
          const int b = m >> 10, t = m & 1023, hh = n >> 6, d = n & 63;
          ((bf16*)outp)[((size_t)((b << 4) + hh) << 16) + (t << 6) + d] =
              __float2bfloat16(val);
        } else {
          ((float*)outp)[(size_t)m * 1024 + n] = val;
        }
      }
    }
  }
}

// q,k projections: split-bf16 for near-fp32 logit accuracy
__global__ __launch_bounds__(256) void qk_gemm(const float* q_in,
                                               const float* k_in,
                                               const float* Wq, const float* Wk,
                                               const float* bq, const float* bk,
                                               float* qf, float* kf) {
  const int z = blockIdx.z;
  gemm_body<false, true>((z == 0) ? q_in : k_in, (z == 0) ? Wq : Wk,
                         (z == 0) ? bq : bk, (z == 0) ? (void*)qf : (void*)kf,
                         0);
}

__global__ __launch_bounds__(256) void v_gemm(const float* v_in,
                                              const float* Wv, const float* bv,
                                              bf16* vb) {
  gemm_body<false, false>(v_in, Wv, bv, vb, 1);
}

__global__ __launch_bounds__(256) void out_gemm(const bf16* A, const float* Wo,
                                                const float* bo, float* out) {
  gemm_body<true, false>(A, Wo, bo, out, 2);
}

// ---------- fused attention (fp32 VALU flash, online softmax) ----------
// grid: B*H*(T/64) = 1024 blocks, 256 threads.
// thread (tr,tc) = (tid>>4, tid&15): rows tr*4+i, cols tc*4+j. 4x4 scores.
// logits L = 8*(qk + rpe); softmax in exp2 domain. No +/-inf (fast-math safe).
__global__ __launch_bounds__(256) void attn_fused(
    const float* __restrict__ qf, const float* __restrict__ kf,
    const bf16* __restrict__ vb, const float* __restrict__ qraw,
    const float* __restrict__ rel, bf16* __restrict__ ao) {
  __shared__ alignas(16) float qs[4096];    // q tile fp32 [64][64] swizzled
  __shared__ alignas(16) float kps[4096];   // K tile / P alias
  __shared__ alignas(16) float vs[4096];    // V tile
  __shared__ alignas(16) float rqs[4096];   // raw-query tile (rpe operand)
  __shared__ alignas(16) float rels[8128];  // 127 rel rows fp32

  const int bid = blockIdx.x;
  const int ttile = bid & 15;
  const int bh = bid >> 4;
  const int b = bh >> 4, h = bh & 15;
  const int t0 = ttile << 6;
  const int tid = threadIdx.x;
  const int tr = tid >> 4, tc = tid & 15;

  // stage q (fp32 projected) and raw query once
  for (int i = tid; i < 1024; i += 256) {
    const int row = i >> 4, c4 = i & 15;
    *(float4*)(qs + swz(row, c4)) =
        *(const float4*)(qf + (size_t)(bh * 1024 + t0 + row) * 64 + (c4 << 2));
    *(float4*)(rqs + swz(row, c4)) = *(const float4*)(
        qraw + (size_t)(b * 1024 + t0 + row) * 1024 + h * 64 + (c4 << 2));
  }

  float m2[4], lsum[4];
  float4 Oacc[4];
#pragma unroll
  for (int i = 0; i < 4; ++i) {
    m2[i] = -1e30f;
    lsum[i] = 0.f;
    Oacc[i] = make_float4(0.f, 0.f, 0.f, 0.f);
  }

  for (int s0 = 0; s0 < 1024; s0 += 64) {
    __syncthreads();  // prev iter's P/V reads complete before restage
    for (int i = tid; i < 1024; i += 256) {
      const int row = i >> 4, c4 = i & 15;
      *(float4*)(kps + swz(row, c4)) = *(const float4*)(
          kf + (size_t)(bh * 1024 + s0 + row) * 64 + (c4 << 2));
      *(float4*)(vs + swz(row, c4)) =
          ldbf4(vb + (size_t)(bh * 1024 + s0 + row) * 64 + (c4 << 2));
    }
    const int base = s0 - t0 + 999 - 63;  // rel row for u_local=0
    for (int i = tid; i < 127 * 16; i += 256) {
      const int row = i >> 4, c4 = i & 15;
      int ridx = base + row;
      ridx = ridx < 0 ? 0 : (ridx > 1998 ? 1998 : ridx);
      *(float4*)(rels + swz(row, c4)) =
          *(const float4*)(rel + (size_t)ridx * 64 + (c4 << 2));
    }
    __syncthreads();

    float acc[4][4];
#pragma unroll
    for (int i = 0; i < 4; ++i)
#pragma unroll
      for (int j = 0; j < 4; ++j) acc[i][j] = 0.f;

    // content scores: q . k
#pragma unroll 4
    for (int c4 = 0; c4 < 16; ++c4) {
      float4 qv[4], kv[4];
#pragma unroll
      for (int i = 0; i < 4; ++i)
        qv[i] = *(const float4*)(qs + swz(tr * 4 + i, c4));
#pragma unroll
      for (int j = 0; j < 4; ++j)
        kv[j] = *(const float4*)(kps + swz(tc * 4 + j, c4));
#pragma unroll
      for (int i = 0; i < 4; ++i)
#pragma unroll
        for (int j = 0; j < 4; ++j)
          acc[i][j] += qv[i].x * kv[j].x + qv[i].y * kv[j].y +
                       qv[i].z * kv[j].z + qv[i].w * kv[j].w;
    }

    // rpe scores: raw_q . rel[s-t+999]; u_local = dd + (j-i), dd = 4(tc-tr)+63
    const int dd = 4 * (tc - tr) + 63;  // in [3,123]
#pragma unroll 4
    for (int c4 = 0; c4 < 16; ++c4) {
      float4 rq[4], re[7];
#pragma unroll
      for (int i = 0; i < 4; ++i)
        rq[i] = *(const float4*)(rqs + swz(tr * 4 + i, c4));
#pragma unroll
      for (int t = 0; t < 7; ++t)
        re[t] = *(const float4*)(rels + swz(dd - 3 + t, c4));
#pragma unroll
      for (int i = 0; i < 4; ++i)
#pragma unroll
        for (int j = 0; j < 4; ++j) {
          const float4 e = re[j - i + 3];
          acc[i][j] += rq[i].x * e.x + rq[i].y * e.y + rq[i].z * e.z +
                       rq[i].w * e.w;
        }
    }
    __syncthreads();  // all K reads done; kps becomes P

    // online softmax (exp2 domain, logits *= 8*log2e)
    const float SC = 11.5415603172297466f;  // 8 * log2(e)
#pragma unroll
    for (int i = 0; i < 4; ++i) {
      const float Lx = acc[i][0] * SC, Ly = acc[i][1] * SC;
      const float Lz = acc[i][2] * SC, Lw = acc[i][3] * SC;
      float tm = fmaxf(fmaxf(Lx, Ly), fmaxf(Lz, Lw));
      tm = fmaxf(tm, __shfl_xor(tm, 1));
      tm = fmaxf(tm, __shfl_xor(tm, 2));
      tm = fmaxf(tm, __shfl_xor(tm, 4));
      tm = fmaxf(tm, __shfl_xor(tm, 8));
      const float nm = fmaxf(m2[i], tm);
      const float al = ex2(m2[i] - nm);  // finite args only
      m2[i] = nm;
      float4 p;
      p.x = ex2(Lx - nm);
      p.y = ex2(Ly - nm);
      p.z = ex2(Lz - nm);
      p.w = ex2(Lw - nm);
      float rs = p.x + p.y + p.z + p.w;
      rs += __shfl_xor(rs, 1);
      rs += __shfl_xor(rs, 2);
      rs += __shfl_xor(rs, 4);
      rs += __shfl_xor(rs, 8);
      lsum[i] = lsum[i] * al + rs;
      Oacc[i].x *= al;
      Oacc[i].y *= al;
      Oacc[i].z *= al;
      Oacc[i].w *= al;
      *(float4*)(kps + swz(tr * 4 + i, tc)) = p;  // P[row][tc*4..+3]
    }
    __syncthreads();

    // PV: O[row][tc*4+c] += sum_s P[row][s] * V[s][tc*4+c]
#pragma unroll 4
    for (int sc = 0; sc < 16; ++sc) {
      float4 pv[4], vv[4];
#pragma unroll
      for (int i = 0; i < 4; ++i)
        pv[i] = *(const float4*)(kps + swz(tr * 4 + i, sc));
#pragma unroll
      for (int k = 0; k < 4; ++k)
        vv[k] = *(const float4*)(vs + swz(sc * 4 + k, tc));
#pragma unroll
      for (int i = 0; i < 4; ++i) {
        Oacc[i].x += pv[i].x * vv[0].x + pv[i].y * vv[1].x + pv[i].z * vv[2].x +
                     pv[i].w * vv[3].x;
        Oacc[i].y += pv[i].x * vv[0].y + pv[i].y * vv[1].y + pv[i].z * vv[2].y +
                     pv[i].w * vv[3].y;
        Oacc[i].z += pv[i].x * vv[0].z + pv[i].y * vv[1].z + pv[i].z * vv[2].z +
                     pv[i].w * vv[3].z;
        Oacc[i].w += pv[i].x * vv[0].w + pv[i].y * vv[1].w + pv[i].z * vv[2].w +
                     pv[i].w * vv[3].w;
      }
    }
  }

  // epilogue -> attn output bf16 [B*T, H*hd] (GEMM-ready layout)
#pragma unroll
  for (int i = 0; i < 4; ++i) {
    const float inv = 1.f / lsum[i];
    const int t = t0 + tr * 4 + i;
    bf16* op = ao + (size_t)(b * 1024 + t) * 1024 + h * 64 + tc * 4;
    op[0] = __float2bfloat16(Oacc[i].x * inv);
    op[1] = __float2bfloat16(Oacc[i].y * inv);
    op[2] = __float2bfloat16(Oacc[i].z * inv);
    op[3] = __float2bfloat16(Oacc[i].w * inv);
  }
}

// ---------- launch ----------
extern "C" void kernel_launch(void* const* d_in, const int* in_sizes, int n_in,
                              void* d_out, int out_size, void* d_ws,
                              size_t ws_size, hipStream_t stream) {
  const float* query = (const float*)d_in[0];
  const float* key = (const float*)d_in[1];
  const float* value = (const float*)d_in[2];
  const float* Wq = (const float*)d_in[3];
  const float* bq = (const float*)d_in[4];
  const float* Wk = (const float*)d_in[5];
  const float* bk = (const float*)d_in[6];
  const float* Wv = (const float*)d_in[7];
  const float* bv = (const float*)d_in[8];
  const float* Wo = (const float*)d_in[9];
  const float* bo = (const float*)d_in[10];
  const float* rel = (const float*)d_in[11];

  char* ws = (char*)d_ws;
  float* qf = (float*)ws;                         // 16 MB fp32 [B,H,T,hd]
  float* kf = (float*)(ws + ((size_t)16 << 20));  // 16 MB fp32 [B,H,T,hd]
  bf16* vb = (bf16*)(ws + ((size_t)32 << 20));    // 8 MB bf16 [B,H,T,hd]
  bf16* ao = (bf16*)(ws + ((size_t)40 << 20));    // 8 MB bf16 [B*T, 1024]
  float* out = (float*)d_out;

  qk_gemm<<<dim3(32, 8, 2), 256, 0, stream>>>(query, key, Wq, Wk, bq, bk, qf,
                                              kf);
  v_gemm<<<dim3(32, 8), 256, 0, stream>>>(value, Wv, bv, vb);
  attn_fused<<<1024, 256, 0, stream>>>(qf, kf, vb, query, rel, ao);
  out_gemm<<<dim3(32, 8), 256, 0, stream>>>(ao, Wo, bo, out);
}

// Round 5
// 401.457 us; speedup vs baseline: 2.7611x; 2.7611x over previous
//
#include <hip/hip_runtime.h>
#include <hip/hip_bf16.h>
#include <math.h>

typedef __hip_bfloat16 bf16;
typedef __attribute__((ext_vector_type(8))) short short8;
typedef __attribute__((ext_vector_type(4))) float f32x4;

// ---------- helpers ----------

__device__ __forceinline__ short f2bs(float x) {
  bf16 h = __float2bfloat16(x);
  return *reinterpret_cast<short*>(&h);
}

__device__ __forceinline__ float bs2f(short s) {
  unsigned int u = ((unsigned int)(unsigned short)s) << 16;
  return __uint_as_float(u);
}

// split x into hi (bf16) + lo (bf16 of residual); hi+lo ~ 2^-18 relative
__device__ __forceinline__ void splitbf(float x, short& hi, short& lo) {
  hi = f2bs(x);
  lo = f2bs(x - bs2f(hi));
}

__device__ __forceinline__ float ex2(float x) {
  return __builtin_amdgcn_exp2f(x);
}

// ---------- MFMA NT GEMM: C[m,n] = sum_k A[m,k]*Bt[n,k] + bias[n] ----------
// M=4096,N=1024,K=1024. 128x128 tile, 4 waves, 16x16x32 bf16 MFMA.
// SPLIT: 3-pass split-bf16 input compute (fp32-grade result) for q,k proj.
// MODE 0: split fp32 result -> hi/lo bf16 buffers at [B,H,T,64]
// MODE 1: bf16 out transposed per-head: vt[(bh*64+d)*1024 + t]
// MODE 2: fp32 out row-major [M,N]
template <bool A_BF16, bool SPLIT, int MODE>
__device__ __forceinline__ void gemm_body(const void* __restrict__ Ap,
                                          const float* __restrict__ Bt,
                                          const float* __restrict__ bias,
                                          void* __restrict__ out0,
                                          void* __restrict__ out1) {
  __shared__ alignas(16) bf16 Ah[128 * 32];
  __shared__ alignas(16) bf16 Bh[128 * 32];
  __shared__ alignas(16) bf16 Al[SPLIT ? 128 * 32 : 1];
  __shared__ alignas(16) bf16 Bl[SPLIT ? 128 * 32 : 1];
  const int tid = threadIdx.x;
  const int wave = tid >> 6;
  const int lane = tid & 63;
  const int wm = wave >> 1, wn = wave & 1;
  const int tm0 = blockIdx.x * 128, tn0 = blockIdx.y * 128;
  const int lrow = lane & 15;
  const int kq = lane >> 4;

  f32x4 acc[4][4];
#pragma unroll
  for (int i = 0; i < 4; ++i)
#pragma unroll
    for (int j = 0; j < 4; ++j) acc[i][j] = (f32x4){0.f, 0.f, 0.f, 0.f};

  for (int k0 = 0; k0 < 1024; k0 += 32) {
    __syncthreads();
#pragma unroll
    for (int rep = 0; rep < 2; ++rep) {
      const int idx = rep * 256 + tid;
      const int row = idx >> 2;
      const int c8 = (idx & 3) * 8;
      if (A_BF16) {
        *(short8*)(Ah + row * 32 + c8) = *(const short8*)(
            (const bf16*)Ap + (size_t)(tm0 + row) * 1024 + k0 + c8);
      } else {
        const float* ga =
            (const float*)Ap + (size_t)(tm0 + row) * 1024 + k0 + c8;
        float4 f0 = *(const float4*)ga;
        float4 f1 = *(const float4*)(ga + 4);
        float av[8] = {f0.x, f0.y, f0.z, f0.w, f1.x, f1.y, f1.z, f1.w};
        short8 sh, sl;
#pragma unroll
        for (int e = 0; e < 8; ++e) {
          short hi, lo;
          splitbf(av[e], hi, lo);
          sh[e] = hi;
          sl[e] = lo;
        }
        *(short8*)(Ah + row * 32 + c8) = sh;
        if (SPLIT) *(short8*)(Al + row * 32 + c8) = sl;
      }
      const float* gb = Bt + (size_t)(tn0 + row) * 1024 + k0 + c8;
      float4 g0 = *(const float4*)gb;
      float4 g1 = *(const float4*)(gb + 4);
      float bv[8] = {g0.x, g0.y, g0.z, g0.w, g1.x, g1.y, g1.z, g1.w};
      short8 sh, sl;
#pragma unroll
      for (int e = 0; e < 8; ++e) {
        short hi, lo;
        splitbf(bv[e], hi, lo);
        sh[e] = hi;
        sl[e] = lo;
      }
      *(short8*)(Bh + row * 32 + c8) = sh;
      if (SPLIT) *(short8*)(Bl + row * 32 + c8) = sl;
    }
    __syncthreads();
    short8 afh[4], bfh[4];
#pragma unroll
    for (int i = 0; i < 4; ++i)
      afh[i] = *(const short8*)(Ah + (wm * 64 + i * 16 + lrow) * 32 + kq * 8);
#pragma unroll
    for (int j = 0; j < 4; ++j)
      bfh[j] = *(const short8*)(Bh + (wn * 64 + j * 16 + lrow) * 32 + kq * 8);
#pragma unroll
    for (int i = 0; i < 4; ++i)
#pragma unroll
      for (int j = 0; j < 4; ++j)
        acc[i][j] = __builtin_amdgcn_mfma_f32_16x16x32_bf16(afh[i], bfh[j],
                                                            acc[i][j], 0, 0, 0);
    if (SPLIT) {
      short8 afl[4], bfl[4];
#pragma unroll
      for (int i = 0; i < 4; ++i)
        afl[i] = *(const short8*)(Al + (wm * 64 + i * 16 + lrow) * 32 + kq * 8);
#pragma unroll
      for (int j = 0; j < 4; ++j)
        bfl[j] = *(const short8*)(Bl + (wn * 64 + j * 16 + lrow) * 32 + kq * 8);
#pragma unroll
      for (int i = 0; i < 4; ++i)
#pragma unroll
        for (int j = 0; j < 4; ++j) {
          acc[i][j] = __builtin_amdgcn_mfma_f32_16x16x32_bf16(
              afh[i], bfl[j], acc[i][j], 0, 0, 0);
          acc[i][j] = __builtin_amdgcn_mfma_f32_16x16x32_bf16(
              afl[i], bfh[j], acc[i][j], 0, 0, 0);
        }
    }
  }

#pragma unroll
  for (int j = 0; j < 4; ++j) {
    const int n = tn0 + wn * 64 + j * 16 + lrow;
    const float bval = bias[n];
#pragma unroll
    for (int i = 0; i < 4; ++i) {
      const int rowb = wm * 64 + i * 16 + kq * 4;
#pragma unroll
      for (int r = 0; r < 4; ++r) {
        const int m = tm0 + rowb + r;
        const float val = acc[i][j][r] + bval;
        if (MODE == 0) {
          const int b = m >> 10, t = m & 1023, hh = n >> 6, d = n & 63;
          const size_t idx = ((size_t)((b << 4) + hh) << 16) + (t << 6) + d;
          short hi, lo;
          splitbf(val, hi, lo);
          ((short*)out0)[idx] = hi;
          ((short*)out1)[idx] = lo;
        } else if (MODE == 1) {
          const int b = m >> 10, t = m & 1023, hh = n >> 6, d = n & 63;
          ((bf16*)out0)[(((size_t)((b << 4) + hh) * 64 + d) << 10) + t] =
              __float2bfloat16(val);
        } else {
          ((float*)out0)[(size_t)m * 1024 + n] = val;
        }
      }
    }
  }
}

// q,k projections: split-input (fp32-grade), split-output hi/lo bf16
__global__ __launch_bounds__(256) void qk_gemm(const float* q_in,
                                               const float* k_in,
                                               const float* Wq, const float* Wk,
                                               const float* bq, const float* bk,
                                               bf16* qhi, bf16* qlo, bf16* khi,
                                               bf16* klo) {
  const int z = blockIdx.z;
  gemm_body<false, true, 0>((z == 0) ? q_in : k_in, (z == 0) ? Wq : Wk,
                            (z == 0) ? bq : bk, (z == 0) ? (void*)qhi : (void*)khi,
                            (z == 0) ? (void*)qlo : (void*)klo);
}

__global__ __launch_bounds__(256) void v_gemm(const float* v_in,
                                              const float* Wv, const float* bv,
                                              bf16* vt) {
  gemm_body<false, false, 1>(v_in, Wv, bv, vt, nullptr);
}

__global__ __launch_bounds__(256) void out_gemm(const bf16* A, const float* Wo,
                                                const float* bo, float* out) {
  gemm_body<true, false, 2>(A, Wo, bo, out, nullptr);
}

// ---------- prep: bf16 copies of raw query (per-head) and rel ----------
__global__ __launch_bounds__(256) void prep(const float* __restrict__ qraw,
                                            const float* __restrict__ rel,
                                            bf16* __restrict__ qrb,
                                            bf16* __restrict__ relb) {
  const int i = blockIdx.x * 256 + threadIdx.x;
  const int NQ = 4 * 16 * 1024 * 64;  // 4194304
  if (i < NQ) {
    const int d = i & 63;
    const int t = (i >> 6) & 1023;
    const int bh = i >> 16;
    const int b = bh >> 4, h = bh & 15;
    qrb[i] =
        __float2bfloat16(qraw[((size_t)(b * 1024 + t)) * 1024 + h * 64 + d]);
  } else {
    const int j = i - NQ;
    if (j < 2000 * 64) {
      const int row = j >> 6;
      relb[j] = __float2bfloat16(row < 1999 ? rel[j] : 0.f);
    }
  }
}

// ---------- MFMA fused attention ----------
// grid 1024 = (bh, ttile); 256 threads = 4 waves; wave w owns q rows
// t0+w*16..+15. Per s-tile (64): QK split-bf16 MFMA, RPE via G=rq.rel^T MFMA
// + Toeplitz gather, online softmax, PV MFMA. LDS 65 KB -> 2 blocks/CU.
__global__ __launch_bounds__(256) void attn_mfma(
    const bf16* __restrict__ qhi, const bf16* __restrict__ qlo,
    const bf16* __restrict__ khi, const bf16* __restrict__ klo,
    const bf16* __restrict__ vt, const bf16* __restrict__ qrb,
    const bf16* __restrict__ relb, bf16* __restrict__ ao) {
  __shared__ alignas(16) bf16 Kh[4096];   // K hi tile [s][d] swizzled
  __shared__ alignas(16) bf16 Kl[4096];   // K lo tile
  __shared__ alignas(16) bf16 VtS[4096];  // V^T tile [d][s] swizzled
  __shared__ alignas(16) bf16 Rl[8192];   // 128 rel rows [u][d] swizzled
  __shared__ alignas(16) bf16 Gs[8704];   // G per wave [16][136]
  __shared__ alignas(16) bf16 Ps[4096];   // P tile [t][s] swizzled

  const int bid = blockIdx.x;
  const int ttile = bid & 15;
  const int bh = bid >> 4;
  const int b = bh >> 4, h = bh & 15;
  const int t0 = ttile << 6;
  const int tid = threadIdx.x;
  const int w = tid >> 6;
  const int lane = tid & 63;
  const int l15 = lane & 15;
  const int kq = lane >> 4;

  // Q / raw-Q A-fragments (registers, reused all s-tiles)
  const int tq = t0 + w * 16 + l15;  // A-frag m row
  const size_t qoff = ((size_t)bh * 1024 + tq) * 64 + kq * 8;
  short8 aqh[2], aql[2], arq[2];
#pragma unroll
  for (int ks = 0; ks < 2; ++ks) {
    aqh[ks] = *(const short8*)(qhi + qoff + ks * 32);
    aql[ks] = *(const short8*)(qlo + qoff + ks * 32);
    arq[ks] = *(const short8*)(qrb + qoff + ks * 32);
  }

  float m2[4], ls[4];
  f32x4 O[4];
#pragma unroll
  for (int r = 0; r < 4; ++r) {
    m2[r] = -1e30f;
    ls[r] = 0.f;
  }
#pragma unroll
  for (int db = 0; db < 4; ++db) O[db] = (f32x4){0.f, 0.f, 0.f, 0.f};

  const int gbase = w * 2176;      // Gs elems per wave: 16*136
  const int trow = w * 16 + kq * 4;  // this lane's S/O row base (local)

  for (int s0 = 0; s0 < 1024; s0 += 64) {
    __syncthreads();
    // ---- stage K hi/lo, Vt, rel (swizzled 16B chunks) ----
    for (int i = tid; i < 512; i += 256) {
      const int row = i >> 3, c = i & 7;
      const int dst = row * 64 + ((c ^ (row & 7)) << 3);
      const size_t src = ((size_t)(bh * 1024 + s0 + row)) * 64 + c * 8;
      *(short8*)(Kh + dst) = *(const short8*)(khi + src);
      *(short8*)(Kl + dst) = *(const short8*)(klo + src);
    }
    for (int i = tid; i < 512; i += 256) {
      const int row = i >> 3, c = i & 7;  // row = d
      *(short8*)(VtS + row * 64 + ((c ^ (row & 7)) << 3)) = *(const short8*)(
          vt + ((size_t)bh * 64 + row) * 1024 + s0 + c * 8);
    }
    const int base = s0 - t0 + 999 - 63;
    for (int i = tid; i < 1024; i += 256) {
      const int row = i >> 3, c = i & 7;
      int ridx = base + row;
      ridx = ridx < 0 ? 0 : (ridx > 1998 ? 1998 : ridx);
      *(short8*)(Rl + row * 64 + ((c ^ (row & 7)) << 3)) =
          *(const short8*)(relb + (size_t)ridx * 64 + c * 8);
    }
    __syncthreads();

    // ---- QK^T: S strips, split-bf16 (hh + hl + lh) ----
    f32x4 S[4];
#pragma unroll
    for (int ns = 0; ns < 4; ++ns) {
      f32x4 s = (f32x4){0.f, 0.f, 0.f, 0.f};
      const int kr = ns * 16 + l15;
#pragma unroll
      for (int ks = 0; ks < 2; ++ks) {
        const int c = ((ks * 4 + kq) ^ (kr & 7)) << 3;
        short8 bh_ = *(const short8*)(Kh + kr * 64 + c);
        short8 bl_ = *(const short8*)(Kl + kr * 64 + c);
        s = __builtin_amdgcn_mfma_f32_16x16x32_bf16(aqh[ks], bh_, s, 0, 0, 0);
        s = __builtin_amdgcn_mfma_f32_16x16x32_bf16(aqh[ks], bl_, s, 0, 0, 0);
        s = __builtin_amdgcn_mfma_f32_16x16x32_bf16(aql[ks], bh_, s, 0, 0, 0);
      }
      S[ns] = s;
    }

    // ---- RPE: G[t][u] = rq . rel[u], u-window per wave ----
    f32x4 G[5];
#pragma unroll
    for (int gi = 0; gi < 5; ++gi) {
      f32x4 g = (f32x4){0.f, 0.f, 0.f, 0.f};
      const int ur = (3 - w + gi) * 16 + l15;  // in [0,127]
#pragma unroll
      for (int ks = 0; ks < 2; ++ks) {
        const int c = ((ks * 4 + kq) ^ (ur & 7)) << 3;
        short8 rf = *(const short8*)(Rl + ur * 64 + c);
        g = __builtin_amdgcn_mfma_f32_16x16x32_bf16(arq[ks], rf, g, 0, 0, 0);
      }
      G[gi] = g;
    }
    // write G to own-wave LDS region (C layout scatter)
#pragma unroll
    for (int gi = 0; gi < 5; ++gi) {
      const int uc = (3 - w + gi) * 16 + l15;
#pragma unroll
      for (int r = 0; r < 4; ++r)
        Gs[gbase + (kq * 4 + r) * 136 + uc] = __float2bfloat16(G[gi][r]);
    }

    // ---- gather rpe, scale logits ----
    const float SC = 11.54156032711170727f;  // 8 * log2(e)
#pragma unroll
    for (int ns = 0; ns < 4; ++ns) {
      const int sl = ns * 16 + l15;
#pragma unroll
      for (int r = 0; r < 4; ++r) {
        const int u = sl - (trow + r) + 63;  // in wave's window
        const float g = __bfloat162float(Gs[gbase + (kq * 4 + r) * 136 + u]);
        S[ns][r] = (S[ns][r] + g) * SC;
      }
    }

    // ---- online softmax (exp2 domain) + P write ----
#pragma unroll
    for (int r = 0; r < 4; ++r) {
      float mx = fmaxf(fmaxf(S[0][r], S[1][r]), fmaxf(S[2][r], S[3][r]));
      mx = fmaxf(mx, __shfl_xor(mx, 1));
      mx = fmaxf(mx, __shfl_xor(mx, 2));
      mx = fmaxf(mx, __shfl_xor(mx, 4));
      mx = fmaxf(mx, __shfl_xor(mx, 8));
      const float nm = fmaxf(m2[r], mx);
      const float al = ex2(m2[r] - nm);
      m2[r] = nm;
      const int t = w * 16 + kq * 4 + r;
      float rs = 0.f;
#pragma unroll
      for (int ns = 0; ns < 4; ++ns) {
        const float p = ex2(S[ns][r] - nm);
        rs += p;
        const int sl = ns * 16 + l15;
        Ps[t * 64 + (((sl >> 3) ^ (t & 7)) << 3) + (sl & 7)] =
            __float2bfloat16(p);
      }
      rs += __shfl_xor(rs, 1);
      rs += __shfl_xor(rs, 2);
      rs += __shfl_xor(rs, 4);
      rs += __shfl_xor(rs, 8);
      ls[r] = ls[r] * al + rs;
      O[0][r] *= al;
      O[1][r] *= al;
      O[2][r] *= al;
      O[3][r] *= al;
    }

    // ---- PV: O += P . V  (A = own-wave P rows, B = Vt rows) ----
    const int tp = w * 16 + l15;
#pragma unroll
    for (int ks = 0; ks < 2; ++ks) {
      const int ca = ((ks * 4 + kq) ^ (tp & 7)) << 3;
      short8 pa = *(const short8*)(Ps + tp * 64 + ca);
#pragma unroll
      for (int db = 0; db < 4; ++db) {
        const int vr = db * 16 + l15;
        const int cb = ((ks * 4 + kq) ^ (vr & 7)) << 3;
        short8 vb_ = *(const short8*)(VtS + vr * 64 + cb);
        O[db] =
            __builtin_amdgcn_mfma_f32_16x16x32_bf16(pa, vb_, O[db], 0, 0, 0);
      }
    }
  }

  // ---- epilogue -> ao bf16 [B*T, 1024] ----
#pragma unroll
  for (int r = 0; r < 4; ++r) {
    const float inv = 1.f / ls[r];
    const int t = t0 + trow + r;
    bf16* op = ao + ((size_t)(b * 1024 + t)) * 1024 + h * 64;
#pragma unroll
    for (int db = 0; db < 4; ++db)
      op[db * 16 + l15] = __float2bfloat16(O[db][r] * inv);
  }
}

// ---------- launch ----------
extern "C" void kernel_launch(void* const* d_in, const int* in_sizes, int n_in,
                              void* d_out, int out_size, void* d_ws,
                              size_t ws_size, hipStream_t stream) {
  const float* query = (const float*)d_in[0];
  const float* key = (const float*)d_in[1];
  const float* value = (const float*)d_in[2];
  const float* Wq = (const float*)d_in[3];
  const float* bq = (const float*)d_in[4];
  const float* Wk = (const float*)d_in[5];
  const float* bk = (const float*)d_in[6];
  const float* Wv = (const float*)d_in[7];
  const float* bv = (const float*)d_in[8];
  const float* Wo = (const float*)d_in[9];
  const float* bo = (const float*)d_in[10];
  const float* rel = (const float*)d_in[11];

  char* ws = (char*)d_ws;
  bf16* qhi = (bf16*)ws;                          // 8 MB [B,H,T,64]
  bf16* qlo = (bf16*)(ws + ((size_t)8 << 20));    // 8 MB
  bf16* khi = (bf16*)(ws + ((size_t)16 << 20));   // 8 MB
  bf16* klo = (bf16*)(ws + ((size_t)24 << 20));   // 8 MB
  bf16* vt = (bf16*)(ws + ((size_t)32 << 20));    // 8 MB [B,H,64,T]
  bf16* qrb = (bf16*)(ws + ((size_t)40 << 20));   // 8 MB [B,H,T,64]
  bf16* ao = (bf16*)(ws + ((size_t)48 << 20));    // 8 MB [B*T,1024]
  bf16* relb = (bf16*)(ws + ((size_t)56 << 20));  // 0.25 MB [2000,64]
  float* out = (float*)d_out;

  prep<<<(4194304 + 128000 + 255) / 256, 256, 0, stream>>>(query, rel, qrb,
                                                           relb);
  qk_gemm<<<dim3(32, 8, 2), 256, 0, stream>>>(query, key, Wq, Wk, bq, bk, qhi,
                                              qlo, khi, klo);
  v_gemm<<<dim3(32, 8), 256, 0, stream>>>(value, Wv, bv, vt);
  attn_mfma<<<1024, 256, 0, stream>>>(qhi, qlo, khi, klo, vt, qrb, relb, ao);
  out_gemm<<<dim3(32, 8), 256, 0, stream>>>(ao, Wo, bo, out);
}

// Round 6
// 311.511 us; speedup vs baseline: 3.5584x; 1.2887x over previous
//
#include <hip/hip_runtime.h>
#include <math.h>

typedef _Float16 h16;
typedef __attribute__((ext_vector_type(8))) _Float16 half8;
typedef __attribute__((ext_vector_type(4))) float f32x4;

#define MFMA16(a, b, c) __builtin_amdgcn_mfma_f32_16x16x32_f16((a), (b), (c), 0, 0, 0)

__device__ __forceinline__ float ex2(float x) {
  return __builtin_amdgcn_exp2f(x);
}

// ---------- MFMA NT GEMM: C[m,n] = sum_k A[m,k]*Bt[n,k] + bias[n] ----------
// M=4096 (1024 for out? no: always 4096 rows here), N=1024, K=1024.
// 128x128 tile, 4 waves, 16x16x32 fp16 MFMA, single pass.
// A fp32 (A_F16=false) or fp16 (true). Bt/bias fp32.
// mode 0: fp16 out scattered to [B,H,T,64]; mode 1: fp16 out [B,H,64,T];
// mode 2: fp32 out row-major [M,N].
template <bool A_F16>
__device__ __forceinline__ void gemm_body(const void* __restrict__ Ap,
                                          const float* __restrict__ Bt,
                                          const float* __restrict__ bias,
                                          void* __restrict__ outp, int mode) {
  __shared__ alignas(16) h16 As[128 * 32];
  __shared__ alignas(16) h16 Bs[128 * 32];
  const int tid = threadIdx.x;
  const int wave = tid >> 6;
  const int lane = tid & 63;
  const int wm = wave >> 1, wn = wave & 1;
  const int tm0 = blockIdx.x * 128, tn0 = blockIdx.y * 128;
  const int lrow = lane & 15;
  const int kq = lane >> 4;

  f32x4 acc[4][4];
#pragma unroll
  for (int i = 0; i < 4; ++i)
#pragma unroll
    for (int j = 0; j < 4; ++j) acc[i][j] = (f32x4){0.f, 0.f, 0.f, 0.f};

  for (int k0 = 0; k0 < 1024; k0 += 32) {
    __syncthreads();
#pragma unroll
    for (int rep = 0; rep < 2; ++rep) {
      const int idx = rep * 256 + tid;  // 0..511: 128 rows x 4 chunks(8 elems)
      const int row = idx >> 2;
      const int c8 = (idx & 3) * 8;
      if (A_F16) {
        *(half8*)(As + row * 32 + c8) = *(const half8*)(
            (const h16*)Ap + (size_t)(tm0 + row) * 1024 + k0 + c8);
      } else {
        const float* ga =
            (const float*)Ap + (size_t)(tm0 + row) * 1024 + k0 + c8;
        float4 f0 = *(const float4*)ga;
        float4 f1 = *(const float4*)(ga + 4);
        half8 s;
        s[0] = (h16)f0.x; s[1] = (h16)f0.y; s[2] = (h16)f0.z; s[3] = (h16)f0.w;
        s[4] = (h16)f1.x; s[5] = (h16)f1.y; s[6] = (h16)f1.z; s[7] = (h16)f1.w;
        *(half8*)(As + row * 32 + c8) = s;
      }
      const float* gb = Bt + (size_t)(tn0 + row) * 1024 + k0 + c8;
      float4 g0 = *(const float4*)gb;
      float4 g1 = *(const float4*)(gb + 4);
      half8 sb;
      sb[0] = (h16)g0.x; sb[1] = (h16)g0.y; sb[2] = (h16)g0.z; sb[3] = (h16)g0.w;
      sb[4] = (h16)g1.x; sb[5] = (h16)g1.y; sb[6] = (h16)g1.z; sb[7] = (h16)g1.w;
      *(half8*)(Bs + row * 32 + c8) = sb;
    }
    __syncthreads();
    half8 af[4], bf[4];
#pragma unroll
    for (int i = 0; i < 4; ++i)
      af[i] = *(const half8*)(As + (wm * 64 + i * 16 + lrow) * 32 + kq * 8);
#pragma unroll
    for (int j = 0; j < 4; ++j)
      bf[j] = *(const half8*)(Bs + (wn * 64 + j * 16 + lrow) * 32 + kq * 8);
#pragma unroll
    for (int i = 0; i < 4; ++i)
#pragma unroll
      for (int j = 0; j < 4; ++j) acc[i][j] = MFMA16(af[i], bf[j], acc[i][j]);
  }

  // epilogue: C row = wm*64 + i*16 + kq*4 + r ; col = wn*64 + j*16 + lrow
#pragma unroll
  for (int j = 0; j < 4; ++j) {
    const int n = tn0 + wn * 64 + j * 16 + lrow;
    const float bval = bias[n];
#pragma unroll
    for (int i = 0; i < 4; ++i) {
      const int rowb = wm * 64 + i * 16 + kq * 4;
#pragma unroll
      for (int r = 0; r < 4; ++r) {
        const int m = tm0 + rowb + r;
        const float val = acc[i][j][r] + bval;
        if (mode == 0) {
          const int b = m >> 10, t = m & 1023, hh = n >> 6, d = n & 63;
          ((h16*)outp)[((size_t)((b << 4) + hh) << 16) + (t << 6) + d] =
              (h16)val;
        } else if (mode == 1) {
          const int b = m >> 10, t = m & 1023, hh = n >> 6, d = n & 63;
          ((h16*)outp)[(((size_t)((b << 4) + hh) * 64 + d) << 10) + t] =
              (h16)val;
        } else {
          ((float*)outp)[(size_t)m * 1024 + n] = val;
        }
      }
    }
  }
}

__global__ __launch_bounds__(256) void qkv_gemm(
    const float* q_in, const float* k_in, const float* v_in, const float* Wq,
    const float* Wk, const float* Wv, const float* bq, const float* bk,
    const float* bv, h16* q16, h16* k16, h16* vt16) {
  const int z = blockIdx.z;
  const float* A = (z == 0) ? q_in : (z == 1) ? k_in : v_in;
  const float* Bt = (z == 0) ? Wq : (z == 1) ? Wk : Wv;
  const float* bias = (z == 0) ? bq : (z == 1) ? bk : bv;
  void* outp = (z == 0) ? (void*)q16 : (z == 1) ? (void*)k16 : (void*)vt16;
  gemm_body<false>(A, Bt, bias, outp, (z == 2) ? 1 : 0);
}

__global__ __launch_bounds__(256) void out_gemm(const h16* A, const float* Wo,
                                                const float* bo, float* out) {
  gemm_body<true>(A, Wo, bo, out, 2);
}

// ---------- prep: fp16 copy of rel (row 1999 zeroed) ----------
__global__ __launch_bounds__(256) void prep(const float* __restrict__ rel,
                                            h16* __restrict__ relb) {
  const int j = blockIdx.x * 256 + threadIdx.x;
  if (j < 2000 * 64) {
    const int row = j >> 6;
    relb[j] = (h16)(row < 1999 ? rel[j] : 0.f);
  }
}

// ---------- MFMA fused attention (fp16 single-pass) ----------
// grid 1024 = (bh, ttile); 256 threads = 4 waves; wave w owns q rows
// t0+w*16..+15. Per s-tile (64): QK fp16 MFMA, RPE via G=rq.rel^T MFMA +
// Toeplitz gather, online softmax, PV MFMA.
// LDS 40 KB (Gs aliased over Kh+Rl) -> 4 blocks/CU.
__global__ __launch_bounds__(256, 4) void attn_mfma(
    const h16* __restrict__ q16, const h16* __restrict__ k16,
    const h16* __restrict__ vt16, const float* __restrict__ qraw,
    const h16* __restrict__ relb, h16* __restrict__ ao) {
  __shared__ alignas(16) char smem[40960];
  h16* const Kh = (h16*)smem;             // 8 KB [64][64] swizzled
  h16* const Rl = (h16*)(smem + 8192);    // 16 KB [128][64] swizzled
  h16* const VtS = (h16*)(smem + 24576);  // 8 KB [64][64] swizzled
  h16* const Ps = (h16*)(smem + 32768);   // 8 KB [64][64] swizzled
  h16* const Gs = (h16*)smem;             // alias Kh+Rl: 4 x [16][136] = 17 KB

  const int bid = blockIdx.x;
  const int ttile = bid & 15;
  const int bh = bid >> 4;
  const int b = bh >> 4, h = bh & 15;
  const int t0 = ttile << 6;
  const int tid = threadIdx.x;
  const int w = tid >> 6;
  const int lane = tid & 63;
  const int l15 = lane & 15;
  const int kq = lane >> 4;

  // Q fragment (projected, fp16) + raw-Q fragment (fp32 -> fp16), reused
  const int tq = t0 + w * 16 + l15;
  const size_t qoff = ((size_t)bh * 1024 + tq) * 64 + kq * 8;
  half8 aq[2], arq[2];
#pragma unroll
  for (int ks = 0; ks < 2; ++ks) {
    aq[ks] = *(const half8*)(q16 + qoff + ks * 32);
    const float* rp =
        qraw + ((size_t)(b * 1024 + tq)) * 1024 + h * 64 + kq * 8 + ks * 32;
    float4 r0 = *(const float4*)rp;
    float4 r1 = *(const float4*)(rp + 4);
    half8 a;
    a[0] = (h16)r0.x; a[1] = (h16)r0.y; a[2] = (h16)r0.z; a[3] = (h16)r0.w;
    a[4] = (h16)r1.x; a[5] = (h16)r1.y; a[6] = (h16)r1.z; a[7] = (h16)r1.w;
    arq[ks] = a;
  }

  float m2[4], ls[4];
  f32x4 O[4];
#pragma unroll
  for (int r = 0; r < 4; ++r) {
    m2[r] = -1e30f;
    ls[r] = 0.f;
  }
#pragma unroll
  for (int db = 0; db < 4; ++db) O[db] = (f32x4){0.f, 0.f, 0.f, 0.f};

  const int gbase = w * 2176;        // per-wave Gs region: 16*136 halves
  const int trow = w * 16 + kq * 4;  // lane's block-local t base

  for (int s0 = 0; s0 < 1024; s0 += 64) {
    __syncthreads();  // prev iter fully done (incl. Gs reads) before restage
    for (int i = tid; i < 512; i += 256) {
      const int row = i >> 3, c = i & 7;
      *(half8*)(Kh + row * 64 + ((c ^ (row & 7)) << 3)) = *(const half8*)(
          k16 + ((size_t)(bh * 1024 + s0 + row)) * 64 + c * 8);
    }
    for (int i = tid; i < 512; i += 256) {
      const int row = i >> 3, c = i & 7;  // row = d
      *(half8*)(VtS + row * 64 + ((c ^ (row & 7)) << 3)) = *(const half8*)(
          vt16 + ((size_t)bh * 64 + row) * 1024 + s0 + c * 8);
    }
    const int base = s0 - t0 + 999 - 63;
    for (int i = tid; i < 1024; i += 256) {
      const int row = i >> 3, c = i & 7;
      int ridx = base + row;
      ridx = ridx < 0 ? 0 : (ridx > 1998 ? 1998 : ridx);
      *(half8*)(Rl + row * 64 + ((c ^ (row & 7)) << 3)) =
          *(const half8*)(relb + (size_t)ridx * 64 + c * 8);
    }
    __syncthreads();

    // ---- QK^T strips ----
    f32x4 S[4];
#pragma unroll
    for (int ns = 0; ns < 4; ++ns) {
      f32x4 s = (f32x4){0.f, 0.f, 0.f, 0.f};
      const int kr = ns * 16 + l15;
#pragma unroll
      for (int ks = 0; ks < 2; ++ks) {
        const int c = ((ks * 4 + kq) ^ (kr & 7)) << 3;
        s = MFMA16(aq[ks], *(const half8*)(Kh + kr * 64 + c), s);
      }
      S[ns] = s;
    }

    // ---- G[t][u] = rq . rel[u] (wave's 80-wide u window) ----
    f32x4 G[5];
#pragma unroll
    for (int gi = 0; gi < 5; ++gi) {
      f32x4 g = (f32x4){0.f, 0.f, 0.f, 0.f};
      const int ur = (3 - w + gi) * 16 + l15;
#pragma unroll
      for (int ks = 0; ks < 2; ++ks) {
        const int c = ((ks * 4 + kq) ^ (ur & 7)) << 3;
        g = MFMA16(arq[ks], *(const half8*)(Rl + ur * 64 + c), g);
      }
      G[gi] = g;
    }
    __syncthreads();  // all waves done reading Kh/Rl: Gs may overwrite

    // write G to own-wave Gs region (C-layout scatter)
#pragma unroll
    for (int gi = 0; gi < 5; ++gi) {
      const int uc = (3 - w + gi) * 16 + l15;
#pragma unroll
      for (int r = 0; r < 4; ++r)
        Gs[gbase + (kq * 4 + r) * 136 + uc] = (h16)G[gi][r];
    }

    // ---- gather rpe (own-wave region, wave-synchronous), scale ----
    const float SC = 11.54156032711170727f;  // 8 * log2(e)
#pragma unroll
    for (int ns = 0; ns < 4; ++ns) {
      const int sl = ns * 16 + l15;
#pragma unroll
      for (int r = 0; r < 4; ++r) {
        const int u = sl - (trow + r) + 63;
        const float g = (float)Gs[gbase + (kq * 4 + r) * 136 + u];
        S[ns][r] = (S[ns][r] + g) * SC;
      }
    }

    // ---- online softmax (exp2 domain) + P write (fp16) ----
#pragma unroll
    for (int r = 0; r < 4; ++r) {
      float mx = fmaxf(fmaxf(S[0][r], S[1][r]), fmaxf(S[2][r], S[3][r]));
      mx = fmaxf(mx, __shfl_xor(mx, 1));
      mx = fmaxf(mx, __shfl_xor(mx, 2));
      mx = fmaxf(mx, __shfl_xor(mx, 4));
      mx = fmaxf(mx, __shfl_xor(mx, 8));
      const float nm = fmaxf(m2[r], mx);
      const float al = ex2(m2[r] - nm);
      m2[r] = nm;
      const int t = trow + r;
      float rs = 0.f;
#pragma unroll
      for (int ns = 0; ns < 4; ++ns) {
        const float p = ex2(S[ns][r] - nm);
        rs += p;
        const int sl = ns * 16 + l15;
        Ps[t * 64 + (((sl >> 3) ^ (t & 7)) << 3) + (sl & 7)] = (h16)p;
      }
      rs += __shfl_xor(rs, 1);
      rs += __shfl_xor(rs, 2);
      rs += __shfl_xor(rs, 4);
      rs += __shfl_xor(rs, 8);
      ls[r] = ls[r] * al + rs;
      O[0][r] *= al;
      O[1][r] *= al;
      O[2][r] *= al;
      O[3][r] *= al;
    }

    // ---- PV: O += P.V (A = own-wave P rows, B = VtS rows) ----
    const int tp = w * 16 + l15;
#pragma unroll
    for (int ks = 0; ks < 2; ++ks) {
      const int ca = ((ks * 4 + kq) ^ (tp & 7)) << 3;
      half8 pa = *(const half8*)(Ps + tp * 64 + ca);
#pragma unroll
      for (int db = 0; db < 4; ++db) {
        const int vr = db * 16 + l15;
        const int cb = ((ks * 4 + kq) ^ (vr & 7)) << 3;
        O[db] = MFMA16(pa, *(const half8*)(VtS + vr * 64 + cb), O[db]);
      }
    }
  }

  // ---- epilogue -> ao fp16 [B*T, 1024] ----
#pragma unroll
  for (int r = 0; r < 4; ++r) {
    const float inv = 1.f / ls[r];
    const int t = t0 + trow + r;
    h16* op = ao + ((size_t)(b * 1024 + t)) * 1024 + h * 64;
#pragma unroll
    for (int db = 0; db < 4; ++db) op[db * 16 + l15] = (h16)(O[db][r] * inv);
  }
}

// ---------- launch ----------
extern "C" void kernel_launch(void* const* d_in, const int* in_sizes, int n_in,
                              void* d_out, int out_size, void* d_ws,
                              size_t ws_size, hipStream_t stream) {
  const float* query = (const float*)d_in[0];
  const float* key = (const float*)d_in[1];
  const float* value = (const float*)d_in[2];
  const float* Wq = (const float*)d_in[3];
  const float* bq = (const float*)d_in[4];
  const float* Wk = (const float*)d_in[5];
  const float* bk = (const float*)d_in[6];
  const float* Wv = (const float*)d_in[7];
  const float* bv = (const float*)d_in[8];
  const float* Wo = (const float*)d_in[9];
  const float* bo = (const float*)d_in[10];
  const float* rel = (const float*)d_in[11];

  char* ws = (char*)d_ws;
  h16* q16 = (h16*)ws;                          // 8 MB [B,H,T,64]
  h16* k16 = (h16*)(ws + ((size_t)8 << 20));    // 8 MB [B,H,T,64]
  h16* vt16 = (h16*)(ws + ((size_t)16 << 20));  // 8 MB [B,H,64,T]
  h16* ao = (h16*)(ws + ((size_t)24 << 20));    // 8 MB [B*T,1024]
  h16* relb = (h16*)(ws + ((size_t)32 << 20));  // 0.25 MB [2000,64]
  float* out = (float*)d_out;

  prep<<<500, 256, 0, stream>>>(rel, relb);
  qkv_gemm<<<dim3(32, 8, 3), 256, 0, stream>>>(query, key, value, Wq, Wk, Wv,
                                               bq, bk, bv, q16, k16, vt16);
  attn_mfma<<<1024, 256, 0, stream>>>(q16, k16, vt16, query, relb, ao);
  out_gemm<<<dim3(32, 8), 256, 0, stream>>>(ao, Wo, bo, out);
}

// Round 7
// 288.161 us; speedup vs baseline: 3.8467x; 1.0810x over previous
//
#include <hip/hip_runtime.h>
#include <math.h>

typedef _Float16 h16;
typedef __attribute__((ext_vector_type(4))) _Float16 half4;
typedef __attribute__((ext_vector_type(8))) _Float16 half8;
typedef __attribute__((ext_vector_type(4))) float f32x4;

#define AS1 __attribute__((address_space(1)))
#define AS3 __attribute__((address_space(3)))
#define MFMA16(a, b, c) __builtin_amdgcn_mfma_f32_16x16x32_f16((a), (b), (c), 0, 0, 0)

__device__ __forceinline__ float ex2(float x) {
  return __builtin_amdgcn_exp2f(x);
}

// ---------- convert: fp32 -> fp16 for q/k/v, Wq/Wk/Wv/Wo, rel ----------
__global__ __launch_bounds__(256) void convert(
    const float* __restrict__ q, const float* __restrict__ k,
    const float* __restrict__ v, const float* __restrict__ Wq,
    const float* __restrict__ Wk, const float* __restrict__ Wv,
    const float* __restrict__ Wo, const float* __restrict__ rel, h16* q16c,
    h16* k16c, h16* v16c, h16* Wq16, h16* Wk16, h16* Wv16, h16* Wo16,
    h16* relb) {
  const int i = blockIdx.x * 256 + threadIdx.x;  // float4 units
  if (i >= 4226304) return;
  const float* src;
  h16* dst;
  int off;
  if (i < 1048576) {
    src = q; dst = q16c; off = i;
  } else if (i < 2097152) {
    src = k; dst = k16c; off = i - 1048576;
  } else if (i < 3145728) {
    src = v; dst = v16c; off = i - 2097152;
  } else if (i < 3407872) {
    src = Wq; dst = Wq16; off = i - 3145728;
  } else if (i < 3670016) {
    src = Wk; dst = Wk16; off = i - 3407872;
  } else if (i < 3932160) {
    src = Wv; dst = Wv16; off = i - 3670016;
  } else if (i < 4194304) {
    src = Wo; dst = Wo16; off = i - 3932160;
  } else {
    off = i - 4194304;  // rel: 32000 f4 units; src valid below 31984
    half4 hv = (half4){(h16)0.f, (h16)0.f, (h16)0.f, (h16)0.f};
    if (off < 31984) {
      float4 f = *(const float4*)(rel + (size_t)off * 4);
      hv = (half4){(h16)f.x, (h16)f.y, (h16)f.z, (h16)f.w};
    }
    *(half4*)(relb + (size_t)off * 4) = hv;
    return;
  }
  float4 f = *(const float4*)(src + (size_t)off * 4);
  *(half4*)(dst + (size_t)off * 4) =
      (half4){(h16)f.x, (h16)f.y, (h16)f.z, (h16)f.w};
}

// ---------- 128x128 fp16 NT GEMM, m97-style global_load_lds staging ----------
// C[m,n] = sum_k A[m,k]*Bt[n,k] + bias[n]. M=4096,N=1024,K=1024.
// MODE 0: h16 out scattered [B,H,T,64]; MODE 1: h16 out [B,H,64,T].
template <int MODE>
__device__ __forceinline__ void gemm128_body(const h16* __restrict__ A,
                                             const h16* __restrict__ Bt,
                                             const float* __restrict__ bias,
                                             h16* __restrict__ outp) {
  __shared__ alignas(16) h16 As[128 * 32];
  __shared__ alignas(16) h16 Bs[128 * 32];
  const int tid = threadIdx.x;
  const int wave = tid >> 6;
  const int lane = tid & 63;
  const int wm = wave >> 1, wn = wave & 1;
  const int tm0 = blockIdx.x * 128, tn0 = blockIdx.y * 128;
  const int lrow = lane & 15;
  const int kq = lane >> 4;
  const int srow = lane >> 2;       // staging row within 16-row chunk
  const int scol = (lane & 3) * 8;  // staging col (halves)

  f32x4 acc[4][4];
#pragma unroll
  for (int i = 0; i < 4; ++i)
#pragma unroll
    for (int j = 0; j < 4; ++j) acc[i][j] = (f32x4){0.f, 0.f, 0.f, 0.f};

  for (int k0 = 0; k0 < 1024; k0 += 32) {
    __syncthreads();
#pragma unroll
    for (int rep = 0; rep < 2; ++rep) {
      const int cw = wave * 2 + rep;  // 16-row chunk 0..7
      const int row = cw * 16 + srow;
      __builtin_amdgcn_global_load_lds(
          (const AS1 void*)(A + (size_t)(tm0 + row) * 1024 + k0 + scol),
          (AS3 void*)(As + cw * 512), 16, 0, 0);
      __builtin_amdgcn_global_load_lds(
          (const AS1 void*)(Bt + (size_t)(tn0 + row) * 1024 + k0 + scol),
          (AS3 void*)(Bs + cw * 512), 16, 0, 0);
    }
    __syncthreads();
    half8 af[4], bf[4];
#pragma unroll
    for (int i = 0; i < 4; ++i)
      af[i] = *(const half8*)(As + (wm * 64 + i * 16 + lrow) * 32 + kq * 8);
#pragma unroll
    for (int j = 0; j < 4; ++j)
      bf[j] = *(const half8*)(Bs + (wn * 64 + j * 16 + lrow) * 32 + kq * 8);
#pragma unroll
    for (int i = 0; i < 4; ++i)
#pragma unroll
      for (int j = 0; j < 4; ++j) acc[i][j] = MFMA16(af[i], bf[j], acc[i][j]);
  }

#pragma unroll
  for (int j = 0; j < 4; ++j) {
    const int n = tn0 + wn * 64 + j * 16 + lrow;
    const float bval = bias[n];
#pragma unroll
    for (int i = 0; i < 4; ++i) {
      const int rowb = wm * 64 + i * 16 + kq * 4;
#pragma unroll
      for (int r = 0; r < 4; ++r) {
        const int m = tm0 + rowb + r;
        const float val = acc[i][j][r] + bval;
        const int b = m >> 10, t = m & 1023, hh = n >> 6, d = n & 63;
        if (MODE == 0) {
          outp[((size_t)((b << 4) + hh) << 16) + (t << 6) + d] = (h16)val;
        } else {
          outp[(((size_t)((b << 4) + hh) * 64 + d) << 10) + t] = (h16)val;
        }
      }
    }
  }
}

__global__ __launch_bounds__(256) void qkv_gemm(
    const h16* q16c, const h16* k16c, const h16* v16c, const h16* Wq16,
    const h16* Wk16, const h16* Wv16, const float* bq, const float* bk,
    const float* bv, h16* q16, h16* k16, h16* vt16) {
  const int z = blockIdx.z;
  const h16* A = (z == 0) ? q16c : (z == 1) ? k16c : v16c;
  const h16* Bt = (z == 0) ? Wq16 : (z == 1) ? Wk16 : Wv16;
  const float* bias = (z == 0) ? bq : (z == 1) ? bk : bv;
  if (z == 2)
    gemm128_body<1>(A, Bt, bias, vt16);
  else
    gemm128_body<0>(A, Bt, bias, (z == 0) ? q16 : k16);
}

// ---------- out GEMM: 64x128 tile (512 blocks -> 2/CU), fp32 out ----------
__global__ __launch_bounds__(256) void out_gemm(const h16* __restrict__ A,
                                                const h16* __restrict__ Bt,
                                                const float* __restrict__ bo,
                                                float* __restrict__ out) {
  __shared__ alignas(16) h16 As[64 * 32];
  __shared__ alignas(16) h16 Bs[128 * 32];
  const int tid = threadIdx.x;
  const int wave = tid >> 6;
  const int lane = tid & 63;
  const int wm = wave >> 1, wn = wave & 1;
  const int tm0 = blockIdx.x * 64, tn0 = blockIdx.y * 128;
  const int lrow = lane & 15;
  const int kq = lane >> 4;
  const int srow = lane >> 2;
  const int scol = (lane & 3) * 8;

  f32x4 acc[2][4];
#pragma unroll
  for (int i = 0; i < 2; ++i)
#pragma unroll
    for (int j = 0; j < 4; ++j) acc[i][j] = (f32x4){0.f, 0.f, 0.f, 0.f};

  for (int k0 = 0; k0 < 1024; k0 += 32) {
    __syncthreads();
    {  // A tile: 64x32 = 4 chunks, one per wave
      const int row = wave * 16 + srow;
      __builtin_amdgcn_global_load_lds(
          (const AS1 void*)(A + (size_t)(tm0 + row) * 1024 + k0 + scol),
          (AS3 void*)(As + wave * 512), 16, 0, 0);
    }
#pragma unroll
    for (int rep = 0; rep < 2; ++rep) {  // B tile: 128x32 = 8 chunks
      const int cw = wave * 2 + rep;
      const int row = cw * 16 + srow;
      __builtin_amdgcn_global_load_lds(
          (const AS1 void*)(Bt + (size_t)(tn0 + row) * 1024 + k0 + scol),
          (AS3 void*)(Bs + cw * 512), 16, 0, 0);
    }
    __syncthreads();
    half8 af[2], bf[4];
#pragma unroll
    for (int i = 0; i < 2; ++i)
      af[i] = *(const half8*)(As + (wm * 32 + i * 16 + lrow) * 32 + kq * 8);
#pragma unroll
    for (int j = 0; j < 4; ++j)
      bf[j] = *(const half8*)(Bs + (wn * 64 + j * 16 + lrow) * 32 + kq * 8);
#pragma unroll
    for (int i = 0; i < 2; ++i)
#pragma unroll
      for (int j = 0; j < 4; ++j) acc[i][j] = MFMA16(af[i], bf[j], acc[i][j]);
  }

#pragma unroll
  for (int j = 0; j < 4; ++j) {
    const int n = tn0 + wn * 64 + j * 16 + lrow;
    const float bval = bo[n];
#pragma unroll
    for (int i = 0; i < 2; ++i) {
      const int rowb = wm * 32 + i * 16 + kq * 4;
#pragma unroll
      for (int r = 0; r < 4; ++r) {
        const int m = tm0 + rowb + r;
        out[(size_t)m * 1024 + n] = acc[i][j][r] + bval;
      }
    }
  }
}

// ---------- MFMA fused attention (fp16, shfl-based Toeplitz gather) ----------
// grid 1024 = (bh, ttile); 4 waves; wave w owns q rows t0+w*16..+15.
// Per s-tile: QK MFMA, G=rq.rel^T MFMA + in-register shfl gather, online
// softmax, PV MFMA. LDS 40 KB -> 4 blocks/CU. 2 barriers/s-tile.
__global__ __launch_bounds__(256, 4) void attn_mfma(
    const h16* __restrict__ q16, const h16* __restrict__ k16,
    const h16* __restrict__ vt16, const h16* __restrict__ q16c,
    const h16* __restrict__ relb, h16* __restrict__ ao) {
  __shared__ alignas(16) h16 Kh[4096];   // 8 KB [64][64] swizzled
  __shared__ alignas(16) h16 Rl[8192];   // 16 KB [128][64] swizzled
  __shared__ alignas(16) h16 VtS[4096];  // 8 KB [64][64] swizzled
  __shared__ alignas(16) h16 Ps[4096];   // 8 KB [64][64] swizzled

  const int bid = blockIdx.x;
  const int ttile = bid & 15;
  const int bh = bid >> 4;
  const int b = bh >> 4, h = bh & 15;
  const int t0 = ttile << 6;
  const int tid = threadIdx.x;
  const int w = tid >> 6;
  const int lane = tid & 63;
  const int l15 = lane & 15;
  const int kq = lane >> 4;

  // Q fragment (projected) + raw-Q fragment, fp16, reused across s-tiles
  const int tq = t0 + w * 16 + l15;
  half8 aq[2], arq[2];
#pragma unroll
  for (int ks = 0; ks < 2; ++ks) {
    aq[ks] =
        *(const half8*)(q16 + ((size_t)bh * 1024 + tq) * 64 + kq * 8 + ks * 32);
    arq[ks] = *(const half8*)(q16c + ((size_t)(b * 1024 + tq)) * 1024 + h * 64 +
                              kq * 8 + ks * 32);
  }

  float m2[4], ls[4];
  f32x4 O[4];
#pragma unroll
  for (int r = 0; r < 4; ++r) {
    m2[r] = -1e30f;
    ls[r] = 0.f;
  }
#pragma unroll
  for (int db = 0; db < 4; ++db) O[db] = (f32x4){0.f, 0.f, 0.f, 0.f};

  const int trow = w * 16 + kq * 4;  // lane's block-local t base

  for (int s0 = 0; s0 < 1024; s0 += 64) {
    __syncthreads();  // all waves done reading Kh/Rl/VtS from prev iter
    for (int i = tid; i < 512; i += 256) {
      const int row = i >> 3, c = i & 7;
      *(half8*)(Kh + row * 64 + ((c ^ (row & 7)) << 3)) = *(const half8*)(
          k16 + ((size_t)(bh * 1024 + s0 + row)) * 64 + c * 8);
    }
    for (int i = tid; i < 512; i += 256) {
      const int row = i >> 3, c = i & 7;  // row = d
      *(half8*)(VtS + row * 64 + ((c ^ (row & 7)) << 3)) = *(const half8*)(
          vt16 + ((size_t)bh * 64 + row) * 1024 + s0 + c * 8);
    }
    const int base = s0 - t0 + 999 - 63;
    for (int i = tid; i < 1024; i += 256) {
      const int row = i >> 3, c = i & 7;
      int ridx = base + row;
      ridx = ridx < 0 ? 0 : (ridx > 1998 ? 1998 : ridx);
      *(half8*)(Rl + row * 64 + ((c ^ (row & 7)) << 3)) =
          *(const half8*)(relb + (size_t)ridx * 64 + c * 8);
    }
    __syncthreads();

    // ---- QK^T strips ----
    f32x4 S[4];
#pragma unroll
    for (int ns = 0; ns < 4; ++ns) {
      f32x4 s = (f32x4){0.f, 0.f, 0.f, 0.f};
      const int kr = ns * 16 + l15;
#pragma unroll
      for (int ks = 0; ks < 2; ++ks) {
        const int c = ((ks * 4 + kq) ^ (kr & 7)) << 3;
        s = MFMA16(aq[ks], *(const half8*)(Kh + kr * 64 + c), s);
      }
      S[ns] = s;
    }

    // ---- G[t][u] = rq . rel[u]; wave's u-window [(3-w)*16, (8-w)*16) ----
    f32x4 G[5];
#pragma unroll
    for (int gi = 0; gi < 5; ++gi) {
      f32x4 g = (f32x4){0.f, 0.f, 0.f, 0.f};
      const int ur = (3 - w + gi) * 16 + l15;
#pragma unroll
      for (int ks = 0; ks < 2; ++ks) {
        const int c = ((ks * 4 + kq) ^ (ur & 7)) << 3;
        g = MFMA16(arq[ks], *(const half8*)(Rl + ur * 64 + c), g);
      }
      G[gi] = g;
    }

    // ---- in-register Toeplitz gather + logit scale ----
    // G_mat[kq*4+r][u] lives at lane (kq<<4)|(u&15), reg G[(u>>4)+w-3][r].
    const float SC = 11.54156032711170727f;  // 8 * log2(e)
    const int C0 = 63 - w * 16 - kq * 4;
#pragma unroll
    for (int ns = 0; ns < 4; ++ns) {
#pragma unroll
      for (int r = 0; r < 4; ++r) {
        const int u = l15 + C0 + ns * 16 - r;
        const int src = (kq << 4) | (u & 15);
        const int gsel = (u >> 4) + w - 3;  // in {ns, ns+1}
        const float v0 = __shfl(G[ns][r], src, 64);
        const float v1 = __shfl(G[(ns + 1) <= 4 ? (ns + 1) : 4][r], src, 64);
        const float g = (gsel == ns) ? v0 : v1;
        S[ns][r] = (S[ns][r] + g) * SC;
      }
    }

    // ---- online softmax (exp2 domain) + P write (fp16, own-wave rows) ----
#pragma unroll
    for (int r = 0; r < 4; ++r) {
      float mx = fmaxf(fmaxf(S[0][r], S[1][r]), fmaxf(S[2][r], S[3][r]));
      mx = fmaxf(mx, __shfl_xor(mx, 1));
      mx = fmaxf(mx, __shfl_xor(mx, 2));
      mx = fmaxf(mx, __shfl_xor(mx, 4));
      mx = fmaxf(mx, __shfl_xor(mx, 8));
      const float nm = fmaxf(m2[r], mx);
      const float al = ex2(m2[r] - nm);
      m2[r] = nm;
      const int t = trow + r;
      float rs = 0.f;
#pragma unroll
      for (int ns = 0; ns < 4; ++ns) {
        const float p = ex2(S[ns][r] - nm);
        rs += p;
        const int sl = ns * 16 + l15;
        Ps[t * 64 + (((sl >> 3) ^ (t & 7)) << 3) + (sl & 7)] = (h16)p;
      }
      rs += __shfl_xor(rs, 1);
      rs += __shfl_xor(rs, 2);
      rs += __shfl_xor(rs, 4);
      rs += __shfl_xor(rs, 8);
      ls[r] = ls[r] * al + rs;
      O[0][r] *= al;
      O[1][r] *= al;
      O[2][r] *= al;
      O[3][r] *= al;
    }

    // ---- PV: O += P.V (A = own-wave P rows, B = VtS rows) ----
    const int tp = w * 16 + l15;
#pragma unroll
    for (int ks = 0; ks < 2; ++ks) {
      const int ca = ((ks * 4 + kq) ^ (tp & 7)) << 3;
      half8 pa = *(const half8*)(Ps + tp * 64 + ca);
#pragma unroll
      for (int db = 0; db < 4; ++db) {
        const int vr = db * 16 + l15;
        const int cb = ((ks * 4 + kq) ^ (vr & 7)) << 3;
        O[db] = MFMA16(pa, *(const half8*)(VtS + vr * 64 + cb), O[db]);
      }
    }
  }

  // ---- epilogue -> ao fp16 [B*T, 1024] ----
#pragma unroll
  for (int r = 0; r < 4; ++r) {
    const float inv = 1.f / ls[r];
    const int t = t0 + trow + r;
    h16* op = ao + ((size_t)(b * 1024 + t)) * 1024 + h * 64;
#pragma unroll
    for (int db = 0; db < 4; ++db) op[db * 16 + l15] = (h16)(O[db][r] * inv);
  }
}

// ---------- launch ----------
extern "C" void kernel_launch(void* const* d_in, const int* in_sizes, int n_in,
                              void* d_out, int out_size, void* d_ws,
                              size_t ws_size, hipStream_t stream) {
  const float* query = (const float*)d_in[0];
  const float* key = (const float*)d_in[1];
  const float* value = (const float*)d_in[2];
  const float* Wq = (const float*)d_in[3];
  const float* bq = (const float*)d_in[4];
  const float* Wk = (const float*)d_in[5];
  const float* bk = (const float*)d_in[6];
  const float* Wv = (const float*)d_in[7];
  const float* bv = (const float*)d_in[8];
  const float* Wo = (const float*)d_in[9];
  const float* bo = (const float*)d_in[10];
  const float* rel = (const float*)d_in[11];

  char* ws = (char*)d_ws;
  h16* q16c = (h16*)ws;                          // 8 MB raw query fp16
  h16* k16c = (h16*)(ws + ((size_t)8 << 20));    // 8 MB raw key (ao aliases)
  h16* v16c = (h16*)(ws + ((size_t)16 << 20));   // 8 MB raw value
  h16* Wq16 = (h16*)(ws + ((size_t)24 << 20));   // 2 MB
  h16* Wk16 = (h16*)(ws + ((size_t)26 << 20));   // 2 MB
  h16* Wv16 = (h16*)(ws + ((size_t)28 << 20));   // 2 MB
  h16* Wo16 = (h16*)(ws + ((size_t)30 << 20));   // 2 MB
  h16* q16 = (h16*)(ws + ((size_t)32 << 20));    // 8 MB [B,H,T,64]
  h16* k16 = (h16*)(ws + ((size_t)40 << 20));    // 8 MB [B,H,T,64]
  h16* vt16 = (h16*)(ws + ((size_t)48 << 20));   // 8 MB [B,H,64,T]
  h16* relb = (h16*)(ws + ((size_t)56 << 20));   // 0.25 MB [2000,64]
  h16* ao = k16c;  // k16c dead after qkv_gemm; attn writes ao here
  float* out = (float*)d_out;

  convert<<<16509, 256, 0, stream>>>(query, key, value, Wq, Wk, Wv, Wo, rel,
                                     q16c, k16c, v16c, Wq16, Wk16, Wv16, Wo16,
                                     relb);
  qkv_gemm<<<dim3(32, 8, 3), 256, 0, stream>>>(q16c, k16c, v16c, Wq16, Wk16,
                                               Wv16, bq, bk, bv, q16, k16,
                                               vt16);
  attn_mfma<<<1024, 256, 0, stream>>>(q16, k16, vt16, q16c, relb, ao);
  out_gemm<<<dim3(64, 8), 256, 0, stream>>>(ao, Wo16, bo, out);
}